// Round 2
// baseline (36707.291 us; speedup 1.0000x reference)
//
#include <hip/hip_runtime.h>
#include <hip/hip_cooperative_groups.h>

namespace cg = cooperative_groups;

#define B_ 16
#define T_ 256
#define E_ 512
#define H_ 1024
#define V_ 32000

// ---------------------------------------------------------------------------
// Embedding gather: x0[bt, e] = emb[tokens[bt], e]   (float4 copies)
// ---------------------------------------------------------------------------
__global__ __launch_bounds__(256)
void gather_k(const int* __restrict__ tokens, const float* __restrict__ emb,
              float* __restrict__ x0)
{
    int i  = blockIdx.x * 256 + threadIdx.x;   // float4 index; total 4096*128
    int bt = i >> 7;                           // 128 float4 per row (E=512)
    int e4 = i & 127;
    int tok = tokens[bt];
    ((float4*)x0)[i] = ((const float4*)(emb + (size_t)tok * E_))[e4];
}

// ---------------------------------------------------------------------------
// fp32 SGEMM: C[M,N] = A[M,K] @ B[K,N] + bias[N]
// 128x128 tile, BK=8, 256 threads, 8x8 per thread.
// DO_MASK: rows with tokens[row]==0 get one-hot(0) instead (final logits).
// ---------------------------------------------------------------------------
template<int DO_MASK>
__global__ __launch_bounds__(256)
void sgemm_k(const float* __restrict__ A, const float* __restrict__ Bm,
             const float* __restrict__ bias, float* __restrict__ C,
             const int* __restrict__ tokens, int M, int N, int K)
{
    __shared__ float As[8][128];   // A tile stored transposed [k][m]
    __shared__ float Bs[8][128];   // [k][n]

    const int tid = threadIdx.x;
    const int bm  = blockIdx.y * 128;
    const int bn  = blockIdx.x * 128;
    const int tx  = tid & 15;
    const int ty  = tid >> 4;

    const int arow = tid >> 1;          // 0..127
    const int acol = (tid & 1) * 4;     // 0 or 4
    const int brow = tid >> 5;          // 0..7
    const int bcol = (tid & 31) * 4;    // 0..124

    const float* Ap = A  + (size_t)(bm + arow) * K + acol;
    const float* Bp = Bm + (size_t)brow * N + bn + bcol;

    float acc[8][8];
    #pragma unroll
    for (int i = 0; i < 8; ++i)
        #pragma unroll
        for (int j = 0; j < 8; ++j) acc[i][j] = 0.f;

    for (int kt = 0; kt < K; kt += 8) {
        float4 av = *(const float4*)(Ap + kt);
        float4 bv = *(const float4*)(Bp + (size_t)kt * N);
        __syncthreads();
        As[acol + 0][arow] = av.x;
        As[acol + 1][arow] = av.y;
        As[acol + 2][arow] = av.z;
        As[acol + 3][arow] = av.w;
        *(float4*)&Bs[brow][bcol] = bv;
        __syncthreads();
        #pragma unroll
        for (int k = 0; k < 8; ++k) {
            float4 a0 = *(const float4*)&As[k][ty * 4];
            float4 a1 = *(const float4*)&As[k][ty * 4 + 64];
            float4 b0 = *(const float4*)&Bs[k][tx * 4];
            float4 b1 = *(const float4*)&Bs[k][tx * 4 + 64];
            float a[8] = {a0.x, a0.y, a0.z, a0.w, a1.x, a1.y, a1.z, a1.w};
            float b[8] = {b0.x, b0.y, b0.z, b0.w, b1.x, b1.y, b1.z, b1.w};
            #pragma unroll
            for (int i = 0; i < 8; ++i)
                #pragma unroll
                for (int j = 0; j < 8; ++j)
                    acc[i][j] += a[i] * b[j];
        }
    }

    #pragma unroll
    for (int i = 0; i < 8; ++i) {
        int row = bm + (i >> 2) * 64 + ty * 4 + (i & 3);
        bool msk = true;
        if (DO_MASK) msk = (tokens[row] != 0);
        #pragma unroll
        for (int jh = 0; jh < 2; ++jh) {
            int col = bn + jh * 64 + tx * 4;
            float4 v;
            v.x = acc[i][jh * 4 + 0] + bias[col + 0];
            v.y = acc[i][jh * 4 + 1] + bias[col + 1];
            v.z = acc[i][jh * 4 + 2] + bias[col + 2];
            v.w = acc[i][jh * 4 + 3] + bias[col + 3];
            if (DO_MASK && !msk) {
                v.x = (col == 0) ? 1.f : 0.f;
                v.y = 0.f; v.z = 0.f; v.w = 0.f;
            }
            *(float4*)&C[(size_t)row * N + col] = v;
        }
    }
}

// ---------------------------------------------------------------------------
// Persistent cooperative LSTM layer. Grid = 256 blocks x 256 threads.
// Block bx owns units u0=bx*4..bx*4+3 for all 4 gates -> 16 Wh columns
// j(g,uu) = g*H + u0 + uu, kept in LDS for ALL 256 timesteps (64 KB,
// XOR-swizzled float4 so the 16 distinct row-reads are <=2-way bank-aliased).
// h_prev is read from global (64 KB, L1/L2-broadcast across blocks).
// Thread tid = b*16 + (g*4+uu) computes one gate pre-activation; gates
// combined via __shfl; c-state lives in registers of the g==0 lanes.
// One grid.sync() per timestep.
// ---------------------------------------------------------------------------
__global__ __launch_bounds__(256, 1)
void lstm_layer_k(const float* __restrict__ xz,   // [B*T, 4H] rows bt=b*T+t
                  const float* __restrict__ Wh,   // [H, 4H]
                  float* __restrict__ hseq,       // [B*T, H]
                  const int* __restrict__ tokens) // [B*T]
{
    __shared__ float4 Ws4[16][256];               // 64 KB exactly

    const int tid = threadIdx.x;
    const int u0  = blockIdx.x * 4;

    // one-time load of the block's 16 Wh columns (column-gather, cached)
    for (int f = tid; f < 16 * 256; f += 256) {
        int jj = f >> 8;                          // 0..15
        int k4 = f & 255;
        int g  = jj >> 2, uu = jj & 3;
        const float* wp = Wh + (size_t)(k4 * 4) * (4 * H_) + g * H_ + u0 + uu;
        float4 w = make_float4(wp[0], wp[4 * H_], wp[8 * H_], wp[12 * H_]);
        Ws4[jj][k4 ^ (jj & 7)] = w;
    }
    __syncthreads();

    const int b    = tid >> 4;                    // 0..15
    const int jj   = tid & 15;                    // g*4+uu
    const int g    = jj >> 2;
    const int uu   = jj & 3;
    const int u    = u0 + uu;
    const int j    = g * H_ + u;
    const int lane = tid & 63;
    const int base = lane & 0x33;                 // same (b,uu), g=0 lane

    float c_reg = 0.f;
    cg::grid_group grid = cg::this_grid();

    for (int t = 0; t < T_; ++t) {
        float acc = 0.f;
        if (t > 0) {
            const float4* hp =
                (const float4*)(hseq + ((size_t)(b * T_ + t - 1)) * H_);
            #pragma unroll 8
            for (int k4 = 0; k4 < 256; ++k4) {
                float4 h4 = hp[k4];
                float4 w4 = Ws4[jj][k4 ^ (jj & 7)];
                acc += h4.x * w4.x + h4.y * w4.y + h4.z * w4.z + h4.w * w4.w;
            }
        }
        float z = acc + xz[((size_t)(b * T_ + t)) * (4 * H_) + j];

        float zi = __shfl(z, base, 64);
        float zf = __shfl(z, base + 4, 64);
        float zg = __shfl(z, base + 8, 64);
        float zo = __shfl(z, base + 12, 64);

        if (g == 0) {
            float i_ = 1.f / (1.f + expf(-zi));
            float f_ = 1.f / (1.f + expf(-zf));
            float g_ = tanhf(zg);
            float o_ = 1.f / (1.f + expf(-zo));
            float c_new = f_ * c_reg + i_ * g_;
            float h_new = o_ * tanhf(c_new);
            bool  m  = (tokens[b * T_ + t] != 0);
            float hp_ = (t > 0) ? hseq[((size_t)(b * T_ + t - 1)) * H_ + u] : 0.f;
            float h2 = m ? h_new : hp_;
            c_reg    = m ? c_new : c_reg;
            hseq[((size_t)(b * T_ + t)) * H_ + u] = h2;
        }
        __threadfence();
        grid.sync();
    }
}

// ---------------------------------------------------------------------------
extern "C" void kernel_launch(void* const* d_in, const int* in_sizes, int n_in,
                              void* d_out, int out_size, void* d_ws, size_t ws_size,
                              hipStream_t stream)
{
    const int*   tokens = (const int*)d_in[0];
    const float* emb    = (const float*)d_in[1];
    const float* Wx0    = (const float*)d_in[2];
    const float* Wh0    = (const float*)d_in[3];
    const float* b0     = (const float*)d_in[4];
    const float* Wx1    = (const float*)d_in[5];
    const float* Wh1    = (const float*)d_in[6];
    const float* b1     = (const float*)d_in[7];
    const float* Wout   = (const float*)d_in[8];
    const float* bout   = (const float*)d_in[9];
    float* out = (float*)d_out;

    float* ws = (float*)d_ws;
    float* x0 = ws;                              // 4096*512
    float* xz = x0 + (size_t)4096 * 512;         // 4096*4096 (reused L0/L1)
    float* h0 = xz + (size_t)4096 * 4096;        // 4096*1024
    float* h1 = h0 + (size_t)4096 * 1024;        // 4096*1024

    gather_k<<<2048, 256, 0, stream>>>(tokens, emb, x0);

    dim3 blk(256);
    dim3 g12(4096 / 128, 4096 / 128);
    sgemm_k<0><<<g12, blk, 0, stream>>>(x0, Wx0, b0, xz, nullptr, 4096, 4096, 512);

    {
        void* args[] = {(void*)&xz, (void*)&Wh0, (void*)&h0, (void*)&tokens};
        hipLaunchCooperativeKernel((void*)lstm_layer_k, dim3(256), dim3(256),
                                   args, 0, stream);
    }

    sgemm_k<0><<<g12, blk, 0, stream>>>(h0, Wx1, b1, xz, nullptr, 4096, 4096, 1024);

    {
        void* args[] = {(void*)&xz, (void*)&Wh1, (void*)&h1, (void*)&tokens};
        hipLaunchCooperativeKernel((void*)lstm_layer_k, dim3(256), dim3(256),
                                   args, 0, stream);
    }

    dim3 g3(32000 / 128, 4096 / 128);
    sgemm_k<1><<<g3, blk, 0, stream>>>(h1, Wout, bout, out, tokens, 4096, 32000, 1024);
}

// Round 3
// 12676.034 us; speedup vs baseline: 2.8958x; 2.8958x over previous
//
#include <hip/hip_runtime.h>

#define B_ 16
#define T_ 256
#define E_ 512
#define H_ 1024
#define V_ 32000

// ---------------------------------------------------------------------------
// Embedding gather: x0[bt, e] = emb[tokens[bt], e]   (float4 copies)
// ---------------------------------------------------------------------------
__global__ __launch_bounds__(256)
void gather_k(const int* __restrict__ tokens, const float* __restrict__ emb,
              float* __restrict__ x0)
{
    int i  = blockIdx.x * 256 + threadIdx.x;   // float4 index; total 4096*128
    int bt = i >> 7;                           // 128 float4 per row (E=512)
    int e4 = i & 127;
    int tok = tokens[bt];
    ((float4*)x0)[i] = ((const float4*)(emb + (size_t)tok * E_))[e4];
}

// ---------------------------------------------------------------------------
// fp32 SGEMM: C[M,N] = A[M,K] @ B[K,N] + bias[N]  (unchanged from round 1)
// ---------------------------------------------------------------------------
template<int DO_MASK>
__global__ __launch_bounds__(256)
void sgemm_k(const float* __restrict__ A, const float* __restrict__ Bm,
             const float* __restrict__ bias, float* __restrict__ C,
             const int* __restrict__ tokens, int M, int N, int K)
{
    __shared__ float As[8][128];   // A tile stored transposed [k][m]
    __shared__ float Bs[8][128];   // [k][n]

    const int tid = threadIdx.x;
    const int bm  = blockIdx.y * 128;
    const int bn  = blockIdx.x * 128;
    const int tx  = tid & 15;
    const int ty  = tid >> 4;

    const int arow = tid >> 1;
    const int acol = (tid & 1) * 4;
    const int brow = tid >> 5;
    const int bcol = (tid & 31) * 4;

    const float* Ap = A  + (size_t)(bm + arow) * K + acol;
    const float* Bp = Bm + (size_t)brow * N + bn + bcol;

    float acc[8][8];
    #pragma unroll
    for (int i = 0; i < 8; ++i)
        #pragma unroll
        for (int j = 0; j < 8; ++j) acc[i][j] = 0.f;

    for (int kt = 0; kt < K; kt += 8) {
        float4 av = *(const float4*)(Ap + kt);
        float4 bv = *(const float4*)(Bp + (size_t)kt * N);
        __syncthreads();
        As[acol + 0][arow] = av.x;
        As[acol + 1][arow] = av.y;
        As[acol + 2][arow] = av.z;
        As[acol + 3][arow] = av.w;
        *(float4*)&Bs[brow][bcol] = bv;
        __syncthreads();
        #pragma unroll
        for (int k = 0; k < 8; ++k) {
            float4 a0 = *(const float4*)&As[k][ty * 4];
            float4 a1 = *(const float4*)&As[k][ty * 4 + 64];
            float4 b0 = *(const float4*)&Bs[k][tx * 4];
            float4 b1 = *(const float4*)&Bs[k][tx * 4 + 64];
            float a[8] = {a0.x, a0.y, a0.z, a0.w, a1.x, a1.y, a1.z, a1.w};
            float b[8] = {b0.x, b0.y, b0.z, b0.w, b1.x, b1.y, b1.z, b1.w};
            #pragma unroll
            for (int i = 0; i < 8; ++i)
                #pragma unroll
                for (int j = 0; j < 8; ++j)
                    acc[i][j] += a[i] * b[j];
        }
    }

    #pragma unroll
    for (int i = 0; i < 8; ++i) {
        int row = bm + (i >> 2) * 64 + ty * 4 + (i & 3);
        bool msk = true;
        if (DO_MASK) msk = (tokens[row] != 0);
        #pragma unroll
        for (int jh = 0; jh < 2; ++jh) {
            int col = bn + jh * 64 + tx * 4;
            float4 v;
            v.x = acc[i][jh * 4 + 0] + bias[col + 0];
            v.y = acc[i][jh * 4 + 1] + bias[col + 1];
            v.z = acc[i][jh * 4 + 2] + bias[col + 2];
            v.w = acc[i][jh * 4 + 3] + bias[col + 3];
            if (DO_MASK && !msk) {
                v.x = (col == 0) ? 1.f : 0.f;
                v.y = 0.f; v.z = 0.f; v.w = 0.f;
            }
            *(float4*)&C[(size_t)row * N + col] = v;
        }
    }
}

// ---------------------------------------------------------------------------
// Pre-swizzle Wh [1024][4096] into per-block LDS images:
// WhS[bx][col][k4^  (col&7)] (float4 packs k-direction), bx = unit-quad,
// col = g*4+uu. Makes per-step staging a LINEAR 64 KB copy and LDS reads
// 2-way-bank-aliased (free). Coalesced float4 reads; scattered 4B writes.
// ---------------------------------------------------------------------------
__global__ __launch_bounds__(256)
void wswz_k(const float* __restrict__ Wh, float* __restrict__ WhS)
{
    int i  = blockIdx.x * 256 + threadIdx.x;   // 0 .. 1048575
    int k  = i >> 10;                          // 0..1023
    int j4 = i & 1023;                         // float4 along j
    float4 v = *(const float4*)&Wh[(size_t)k * (4 * H_) + j4 * 4];
    int k4 = k >> 2, e = k & 3;
    float vv[4] = {v.x, v.y, v.z, v.w};
    #pragma unroll
    for (int q = 0; q < 4; ++q) {
        int j   = j4 * 4 + q;
        int u   = j & (H_ - 1);
        int g   = j >> 10;
        int bx  = u >> 2;
        int col = g * 4 + (u & 3);
        int dst = ((bx << 12) + (col << 8) + (k4 ^ (col & 7))) * 4 + e;
        WhS[dst] = vv[q];
    }
}

// ---------------------------------------------------------------------------
// One LSTM timestep. Grid 256 blocks x 256 threads; block bx owns units
// u = bx*4..+3. Stage the block's pre-swizzled 64 KB Wh tile into LDS
// (linear float4 copy), then thread (b = tid>>4, col = tid&15 = g*4+uu)
// computes one gate pre-activation over full K: Wh from LDS (2-way banks),
// h_prev from global (4 rows x 4KB, L1-resident, wave-broadcast).
// Gates combined via __shfl; c-state in global cs[]. Sync = kernel boundary.
// ---------------------------------------------------------------------------
__global__ __launch_bounds__(256)
void lstm_step2_k(const float* __restrict__ xz,   // [B*T, 4H] rows bt=b*T+t
                  const float4* __restrict__ WhS4,
                  float* __restrict__ hseq,       // [B*T, H]
                  float* __restrict__ cs,         // [B, H]
                  const int* __restrict__ tokens, int t)
{
    __shared__ float4 Ws4[4096];                  // exactly 64 KB
    const int tid = threadIdx.x, bx = blockIdx.x;

    const float4* src = WhS4 + (size_t)bx * 4096;
    #pragma unroll 4
    for (int i = tid; i < 4096; i += 256) Ws4[i] = src[i];
    __syncthreads();

    const int b   = tid >> 4;                     // 0..15
    const int col = tid & 15;                     // g*4 + uu
    const int g   = col >> 2;
    const int uu  = col & 3;
    const int u   = bx * 4 + uu;
    const int j   = g * H_ + u;

    float acc = 0.f;
    float hp_ = 0.f;
    if (t > 0) {
        const float4* hp = (const float4*)&hseq[((size_t)(b * T_ + t - 1)) * H_];
        const float4* wp = Ws4 + col * 256;
        const int sw = col & 7;
        float a0 = 0.f, a1 = 0.f, a2 = 0.f, a3 = 0.f;
        #pragma unroll 8
        for (int k4 = 0; k4 < 256; ++k4) {
            float4 h4 = hp[k4];
            float4 w4 = wp[k4 ^ sw];
            a0 += h4.x * w4.x; a1 += h4.y * w4.y;
            a2 += h4.z * w4.z; a3 += h4.w * w4.w;
        }
        acc = (a0 + a1) + (a2 + a3);
        hp_ = hseq[((size_t)(b * T_ + t - 1)) * H_ + u];
    }
    float z = acc + xz[((size_t)(b * T_ + t)) * (4 * H_) + j];

    const int lane = tid & 63;
    const int base = lane & 0x33;                 // g=0 lane of same (b,uu)
    float zi = __shfl(z, base, 64);
    float zf = __shfl(z, base + 4, 64);
    float zg = __shfl(z, base + 8, 64);
    float zo = __shfl(z, base + 12, 64);

    if ((lane & 12) == 0) {                       // g==0 lanes finish (b,u)
        float i_ = 1.f / (1.f + expf(-zi));
        float f_ = 1.f / (1.f + expf(-zf));
        float g_ = tanhf(zg);
        float o_ = 1.f / (1.f + expf(-zo));
        float c_old = (t > 0) ? cs[b * H_ + u] : 0.f;
        float c_new = f_ * c_old + i_ * g_;
        float h_new = o_ * tanhf(c_new);
        bool  m  = (tokens[b * T_ + t] != 0);
        float h2 = m ? h_new : hp_;
        float c2 = m ? c_new : c_old;
        cs[b * H_ + u] = c2;
        hseq[((size_t)(b * T_ + t)) * H_ + u] = h2;
    }
}

// ---------------------------------------------------------------------------
extern "C" void kernel_launch(void* const* d_in, const int* in_sizes, int n_in,
                              void* d_out, int out_size, void* d_ws, size_t ws_size,
                              hipStream_t stream)
{
    const int*   tokens = (const int*)d_in[0];
    const float* emb    = (const float*)d_in[1];
    const float* Wx0    = (const float*)d_in[2];
    const float* Wh0    = (const float*)d_in[3];
    const float* b0     = (const float*)d_in[4];
    const float* Wx1    = (const float*)d_in[5];
    const float* Wh1    = (const float*)d_in[6];
    const float* b1     = (const float*)d_in[7];
    const float* Wout   = (const float*)d_in[8];
    const float* bout   = (const float*)d_in[9];
    float* out = (float*)d_out;

    // Big transient scratch lives inside d_out (131M floats): everything here
    // is dead before the final GEMM overwrites the whole buffer with logits.
    float* scratch = (float*)d_out;
    float* x0  = scratch;                               // 2,097,152 floats
    float* xz  = x0 + (size_t)4096 * 512;               // 16,777,216
    float* WhS = xz + (size_t)4096 * 4096;              // 4,194,304
    // Persistent-across-phases state in d_ws (33.6 MB):
    float* ws = (float*)d_ws;
    float* h0 = ws;                                     // 4,194,304
    float* h1 = h0 + (size_t)4096 * 1024;               // 4,194,304
    float* cst = h1 + (size_t)4096 * 1024;              // 16,384

    gather_k<<<2048, 256, 0, stream>>>(tokens, emb, x0);

    dim3 blk(256);
    dim3 g12(4096 / 128, 4096 / 128);
    sgemm_k<0><<<g12, blk, 0, stream>>>(x0, Wx0, b0, xz, nullptr, 4096, 4096, 512);

    wswz_k<<<4096, 256, 0, stream>>>(Wh0, WhS);
    for (int t = 0; t < T_; ++t)
        lstm_step2_k<<<256, 256, 0, stream>>>(xz, (const float4*)WhS, h0, cst,
                                              tokens, t);

    sgemm_k<0><<<g12, blk, 0, stream>>>(h0, Wx1, b1, xz, nullptr, 4096, 4096, 1024);

    wswz_k<<<4096, 256, 0, stream>>>(Wh1, WhS);
    for (int t = 0; t < T_; ++t)
        lstm_step2_k<<<256, 256, 0, stream>>>(xz, (const float4*)WhS, h1, cst,
                                              tokens, t);

    dim3 g3(32000 / 128, 4096 / 128);
    sgemm_k<1><<<g3, blk, 0, stream>>>(h1, Wout, bout, out, tokens, 4096, 32000, 1024);
}